// Round 10
// baseline (281.238 us; speedup 1.0000x reference)
//
#include <hip/hip_runtime.h>
#include <math.h>

// ---------------------------------------------------------------------------
// Round 21 — K1 -> 256x256 8-phase counted-vmcnt template (guide §5 / m201).
//   Rationale: non-attn time invariant (184->183->180 µs) across three
//   staging rewrites => 128²/2-barrier family plateau (~550 TF). The 8-phase
//   256² family is the documented 1563 TF structure. K1 only (N=3072 -> 384
//   blocks; K3's N=1024 would idle half the CUs at 256², keeps round-20 core).
//   Dynamic LDS 128 KiB with hipFuncSetAttribute; graceful fallback.
//   K0/K2/K3 unchanged.
// ---------------------------------------------------------------------------

typedef __attribute__((ext_vector_type(8))) __bf16 bf16x8;
typedef __attribute__((ext_vector_type(8))) short  short8;
typedef __attribute__((ext_vector_type(4))) short  s16x4;
typedef __attribute__((ext_vector_type(4))) float  f32x4;

#define MFMA16(a, b, c) __builtin_amdgcn_mfma_f32_16x16x32_bf16((a), (b), (c), 0, 0, 0)

static constexpr int    BATCH = 4;
static constexpr int    SEQ   = 2048;
static constexpr int    DIM   = 1024;
static constexpr int    NH    = 16;
static constexpr int    HD    = 64;
static constexpr size_t BHSD  = (size_t)BATCH * NH * SEQ * HD;  // 8388608
static constexpr float  NEGINF = -1e9f;
static constexpr int    PS_LD  = 72;

__device__ __forceinline__ short f2bf(float f) {
    union { float f; unsigned u; } v; v.f = f;
    unsigned r = v.u + 0x7fffu + ((v.u >> 16) & 1u);  // RNE
    return (short)(r >> 16);
}

__device__ __forceinline__ short8 cvt8(const f32x4 lo, const f32x4 hi) {
    short8 r;
    r[0] = f2bf(lo[0]); r[1] = f2bf(lo[1]); r[2] = f2bf(lo[2]); r[3] = f2bf(lo[3]);
    r[4] = f2bf(hi[0]); r[5] = f2bf(hi[1]); r[6] = f2bf(hi[2]); r[7] = f2bf(hi[3]);
    return r;
}

template <bool F32>
__device__ __forceinline__ short8 ld8(const void* p, size_t row, int K, int k) {
    if constexpr (F32) {
        const float* f = (const float*)p;
        f32x4 lo = *(const f32x4*)&f[row * (size_t)K + k];
        f32x4 hi = *(const f32x4*)&f[row * (size_t)K + k + 4];
        return cvt8(lo, hi);
    } else {
        const short* s = (const short*)p;
        return *(const short8*)&s[row * (size_t)K + k];
    }
}

__device__ __forceinline__ void gload16(const void* g, void* lds) {
    __builtin_amdgcn_global_load_lds(
        (const __attribute__((address_space(1))) void*)g,
        (__attribute__((address_space(3))) void*)lds, 16, 0, 0);
}

// ---------------------------------------------------------------------------
// K0: one-shot bf16 conversion of X/Wqkv/Wout + RoPE trig tables.
// ---------------------------------------------------------------------------
__global__ __launch_bounds__(256) void prep_kernel(
    const float* __restrict__ X, const float* __restrict__ Wq,
    const float* __restrict__ Wo, short* __restrict__ Xb,
    short* __restrict__ Wqb, short* __restrict__ Wob,
    float* __restrict__ cosT, float* __restrict__ sinT) {
    const int stride = gridDim.x * blockDim.x;
    for (int idx = blockIdx.x * blockDim.x + threadIdx.x; idx < 3211264; idx += stride) {
        if (idx < 3145728) {
            const float* src; short* dst; int off;
            if (idx < 2097152)      { src = X;  dst = Xb;  off = idx; }
            else if (idx < 2883584) { src = Wq; dst = Wqb; off = idx - 2097152; }
            else                    { src = Wo; dst = Wob; off = idx - 2883584; }
            f32x4 v = *(const f32x4*)&src[(size_t)off * 4];
            s16x4 r;
            r[0] = f2bf(v[0]); r[1] = f2bf(v[1]); r[2] = f2bf(v[2]); r[3] = f2bf(v[3]);
            *(s16x4*)&dst[(size_t)off * 4] = r;
        } else {
            int r = idx - 3145728;
            int s = r >> 5, d = r & 31;
            float ang = (float)s * __expf(-0.28782313662425574f * (float)d);
            float sn, cs;
            sincosf(ang, &sn, &cs);
            cosT[r] = cs; sinT[r] = sn;
        }
    }
}

// ---------------------------------------------------------------------------
// GEMM core (fallback, reg-staged fp32): C(128x128) += A(128xK)*B(128xK)^T.
// ---------------------------------------------------------------------------
template <bool AF32, bool BF32>
__device__ __forceinline__ void gemm128_core(
    const void* __restrict__ A, const void* __restrict__ B, int K,
    short* As, short* Bs, int bm, int bn, f32x4 acc[4][4]) {
    const int tid  = threadIdx.x;
    const int lane = tid & 63;
    const int wave = tid >> 6;
    const int quad = lane >> 4;
    const int col  = lane & 15;
    const int wm   = (wave & 1) * 64;
    const int wn   = (wave >> 1) * 64;

    const int r0 = tid >> 2;
    const int r1 = (tid + 256) >> 2;
    const int ko = (tid & 3) * 8;

#pragma unroll
    for (int i = 0; i < 4; ++i)
#pragma unroll
        for (int j = 0; j < 4; ++j) acc[i][j] = f32x4{0.f, 0.f, 0.f, 0.f};

#pragma unroll 1
    for (int k0 = 0; k0 < K; k0 += 32) {
        short8 a0 = ld8<AF32>(A, (size_t)(bm + r0), K, k0 + ko);
        short8 a1 = ld8<AF32>(A, (size_t)(bm + r1), K, k0 + ko);
        short8 b0 = ld8<BF32>(B, (size_t)(bn + r0), K, k0 + ko);
        short8 b1 = ld8<BF32>(B, (size_t)(bn + r1), K, k0 + ko);
        __syncthreads();
        *(short8*)&As[tid * 8]         = a0;
        *(short8*)&As[(tid + 256) * 8] = a1;
        *(short8*)&Bs[tid * 8]         = b0;
        *(short8*)&Bs[(tid + 256) * 8] = b1;
        __syncthreads();

        bf16x8 af[4], bfr[4];
#pragma unroll
        for (int i = 0; i < 4; ++i)
            af[i] = *(const bf16x8*)&As[(wm + i * 16 + col) * 32 + quad * 8];
#pragma unroll
        for (int j = 0; j < 4; ++j)
            bfr[j] = *(const bf16x8*)&Bs[(wn + j * 16 + col) * 32 + quad * 8];
#pragma unroll
        for (int i = 0; i < 4; ++i)
#pragma unroll
            for (int j = 0; j < 4; ++j)
                acc[i][j] = MFMA16(af[i], bfr[j], acc[i][j]);
    }
}

// ---------------------------------------------------------------------------
// GEMM core p2 (bf16, round-20): BK=64 dbuf gload_lds, counted vmcnt,
// raw barriers, source-pre-swizzled LDS. Used by K3 and K1-fallback.
// ---------------------------------------------------------------------------
__device__ __forceinline__ void gemm128_p2(
    const short* __restrict__ A, const short* __restrict__ B, int K,
    short* As, short* Bs, int bm, int bn, f32x4 acc[4][4]) {
    const int tid  = threadIdx.x;
    const int lane = tid & 63;
    const int wave = tid >> 6;
    const int quad = lane >> 4;
    const int col  = lane & 15;
    const int wm   = (wave & 1) * 64;
    const int wn   = (wave >> 1) * 64;

    const int nt = K >> 6;
    const int rr = tid >> 3;
    const int swk = (((tid & 7) ^ (rr & 7)) << 3);
    const short* Ab = &A[(size_t)(bm + rr) * K + swk];
    const short* Bb = &B[(size_t)(bn + rr) * K + swk];

#pragma unroll
    for (int i = 0; i < 4; ++i)
#pragma unroll
        for (int j = 0; j < 4; ++j) acc[i][j] = f32x4{0.f, 0.f, 0.f, 0.f};

#define STAGE_TILE(c)                                                         \
    {                                                                         \
        const int s_ = (c) & 1;                                               \
        const int k0_ = (c) << 6;                                             \
        _Pragma("unroll")                                                     \
        for (int q = 0; q < 4; ++q) {                                         \
            gload16(Ab + (size_t)(q * 32) * K + k0_,                          \
                    &As[s_ * 8192 + q * 2048 + wave * 512]);                  \
            gload16(Bb + (size_t)(q * 32) * K + k0_,                          \
                    &Bs[s_ * 8192 + q * 2048 + wave * 512]);                  \
        }                                                                     \
    }

    STAGE_TILE(0);
    STAGE_TILE(1);

    const int pc0 = ((quad) ^ (col & 7)) << 3;
    const int pc1 = ((4 | quad) ^ (col & 7)) << 3;

#pragma unroll 1
    for (int c = 0; c < nt; ++c) {
        const int s = c & 1;
        if (c + 1 < nt) { asm volatile("s_waitcnt vmcnt(8)" ::: "memory"); }
        else            { asm volatile("s_waitcnt vmcnt(0)" ::: "memory"); }
        __builtin_amdgcn_s_barrier();

        const short* Asl = &As[s * 8192];
        const short* Bsl = &Bs[s * 8192];
        bf16x8 af[4][2], bfr[4][2];
#pragma unroll
        for (int i = 0; i < 4; ++i) {
            const int r = (wm + i * 16 + col) * 64;
            af[i][0] = *(const bf16x8*)&Asl[r + pc0];
            af[i][1] = *(const bf16x8*)&Asl[r + pc1];
        }
#pragma unroll
        for (int j = 0; j < 4; ++j) {
            const int r = (wn + j * 16 + col) * 64;
            bfr[j][0] = *(const bf16x8*)&Bsl[r + pc0];
            bfr[j][1] = *(const bf16x8*)&Bsl[r + pc1];
        }
#pragma unroll
        for (int kk = 0; kk < 2; ++kk)
#pragma unroll
            for (int i = 0; i < 4; ++i)
#pragma unroll
                for (int j = 0; j < 4; ++j)
                    acc[i][j] = MFMA16(af[i][kk], bfr[j][kk], acc[i][j]);

        __builtin_amdgcn_s_barrier();
        if (c + 2 < nt) STAGE_TILE(c + 2);
    }
#undef STAGE_TILE
}

// ---------------------------------------------------------------------------
// K1 v2: 256x256 tile, BK=64, 512 thr / 8 waves (2Mx4N), 8-phase schedule.
// LDS (dynamic 128 KiB): A[2 buf][2 half][128][64] bf16, B same.
// Per phase: ds_reads (q0: 8 B + 4 A, else 4 A) -> stage 1 half-tile
// (2x gload16) -> [vmcnt(6) at ph4/ph8] -> s_barrier -> 16 MFMA (setprio)
// -> s_barrier. Stage map: ph1 A1(t+1,buf1); ph2-5 tile t+2 -> buf0
// (B0,B1,A0,A1); ph6-8 tile t+3 -> buf1 (B0,B1,A0). vmcnt(6) leaves the 3
// newest half-tiles in flight; everything older is landed (ledger verified).
// Swizzle: round-20 scheme (src k-chunk ^= row&7; read chunk ^= col&7).
// ---------------------------------------------------------------------------
__global__ __launch_bounds__(512, 2) void qkv_rope_256(
    const short* __restrict__ X, const short* __restrict__ W,
    const float* __restrict__ cosT, const float* __restrict__ sinT,
    short* __restrict__ Qo, short* __restrict__ Ko, short* __restrict__ VT) {
    extern __shared__ __align__(16) short smem[];
    short* As = smem;            // 32768 shorts (64 KB)
    short* Bs = smem + 32768;    // 32768 shorts (64 KB)

    const int tid  = threadIdx.x;
    const int lane = tid & 63;
    const int wave = tid >> 6;           // 0..7
    const int quad = lane >> 4;
    const int col  = lane & 15;
    const int wmh  = wave >> 2;          // A half: 0 (rows 0-127) / 1 (128-255)
    const int wn4  = wave & 3;           // B 64-col group
    const int bhalf = wn4 >> 1;          // B half
    const int rbb   = (wn4 & 1) * 64;    // B row base within half

    const int bm = blockIdx.y * 256;     // M block (8192/256 = 32)
    const int bn = blockIdx.x * 256;     // N block (3072/256 = 12)

    // staging geometry
    const int srow = tid >> 3;                       // 0..63
    const int ssw  = (((tid & 7) ^ (srow & 7)) << 3);// swizzled src k (shorts)
    const short* Arow = &X[(size_t)(bm + srow) * 1024 + ssw];
    const short* Brow = &W[(size_t)(bn + srow) * 1024 + ssw];
    const int ldst = (wave * 8) * 64;                // wave dest base (shorts)

    // stage one half-tile of A or B: (tile t, half hf, buf)
#define STG_A(t, hf, buf)                                                     \
    { _Pragma("unroll") for (int g = 0; g < 2; ++g)                           \
        gload16(Arow + (size_t)((hf) * 128 + g * 64) * 1024 + (t) * 64,       \
                &As[(buf) * 16384 + (hf) * 8192 + g * 4096 + ldst]); }
#define STG_B(t, hf, buf)                                                     \
    { _Pragma("unroll") for (int g = 0; g < 2; ++g)                           \
        gload16(Brow + (size_t)((hf) * 128 + g * 64) * 1024 + (t) * 64,       \
                &Bs[(buf) * 16384 + (hf) * 8192 + g * 4096 + ldst]); }

    f32x4 acc[8][4];
#pragma unroll
    for (int i = 0; i < 8; ++i)
#pragma unroll
        for (int j = 0; j < 4; ++j) acc[i][j] = f32x4{0.f, 0.f, 0.f, 0.f};

    const int pck0 = ((quad) ^ (col & 7)) << 3;
    const int pck1 = ((4 | quad) ^ (col & 7)) << 3;

    // prologue: tile0 (4 halves) + tile1 (B0,B1,A0) = 14 loads
    STG_A(0, 0, 0); STG_A(0, 1, 0); STG_B(0, 0, 0); STG_B(0, 1, 0);
    STG_B(1, 0, 1); STG_B(1, 1, 1); STG_A(1, 0, 1);
    asm volatile("s_waitcnt vmcnt(6)" ::: "memory");
    __builtin_amdgcn_s_barrier();

    bf16x8 bfr[4][2];

#pragma unroll 1
    for (int it = 0; it < 8; ++it) {
        const bool last = (it == 7);
        const int t0 = 2 * it;
#pragma unroll
        for (int bh = 0; bh < 2; ++bh) {
            const int buf = bh;
#pragma unroll
            for (int q = 0; q < 4; ++q) {
                const int ph = bh * 4 + q + 1;     // 1..8 (compile-time)
                if (q == 0) {
#pragma unroll
                    for (int nj = 0; nj < 4; ++nj) {
                        const int r = (rbb + nj * 16 + col) * 64;
                        bfr[nj][0] = *(const bf16x8*)&Bs[buf * 16384 + bhalf * 8192 + r + pck0];
                        bfr[nj][1] = *(const bf16x8*)&Bs[buf * 16384 + bhalf * 8192 + r + pck1];
                    }
                }
                bf16x8 af[2][2];
#pragma unroll
                for (int m2 = 0; m2 < 2; ++m2) {
                    const int r = ((q * 2 + m2) * 16 + col) * 64;
                    af[m2][0] = *(const bf16x8*)&As[buf * 16384 + wmh * 8192 + r + pck0];
                    af[m2][1] = *(const bf16x8*)&As[buf * 16384 + wmh * 8192 + r + pck1];
                }
                // stage + waits per phase
                if (ph == 1) { STG_A(t0 + 1, 1, 1); }
                else if (ph == 2) { if (!last) STG_B(t0 + 2, 0, 0); }
                else if (ph == 3) { if (!last) STG_B(t0 + 2, 1, 0); }
                else if (ph == 4) {
                    if (!last) { STG_A(t0 + 2, 0, 0);
                                 asm volatile("s_waitcnt vmcnt(6)" ::: "memory"); }
                    else       { asm volatile("s_waitcnt vmcnt(0)" ::: "memory"); }
                }
                else if (ph == 5) { if (!last) STG_A(t0 + 2, 1, 0); }
                else if (ph == 6) { if (!last) STG_B(t0 + 3, 0, 1); }
                else if (ph == 7) { if (!last) STG_B(t0 + 3, 1, 1); }
                else { /* ph == 8 */
                    if (!last) { STG_A(t0 + 3, 0, 1);
                                 asm volatile("s_waitcnt vmcnt(6)" ::: "memory"); }
                }
                __builtin_amdgcn_s_barrier();
                __builtin_amdgcn_s_setprio(1);
#pragma unroll
                for (int kk = 0; kk < 2; ++kk)
#pragma unroll
                    for (int m2 = 0; m2 < 2; ++m2)
#pragma unroll
                        for (int nj = 0; nj < 4; ++nj)
                            acc[q * 2 + m2][nj] =
                                MFMA16(af[m2][kk], bfr[nj][kk], acc[q * 2 + m2][nj]);
                __builtin_amdgcn_s_setprio(0);
                __builtin_amdgcn_s_barrier();
            }
        }
    }
#undef STG_A
#undef STG_B

    // ---- epilogue: wave owns rows [bm+wmh*128, +128) x cols [n0, n0+64)
    const int n0    = bn + wn4 * 64;
    const int which = n0 >> 10;          // 0=q 1=k 2=v
    const int h     = (n0 >> 6) & 15;

    if (which == 2) {
#pragma unroll
        for (int mi = 0; mi < 8; ++mi) {
            int    m = bm + wmh * 128 + mi * 16 + quad * 4;
            int    b = m >> 11, s = m & 2047;
            size_t rowb = (size_t)(b * NH + h) * HD;
#pragma unroll
            for (int j = 0; j < 4; ++j) {
                int   d = j * 16 + col;
                s16x4 pk;
                pk[0] = f2bf(acc[mi][j][0]); pk[1] = f2bf(acc[mi][j][1]);
                pk[2] = f2bf(acc[mi][j][2]); pk[3] = f2bf(acc[mi][j][3]);
                *(s16x4*)&VT[(rowb + d) * SEQ + s] = pk;
            }
        }
    } else {
        short* dst = which ? Ko : Qo;
#pragma unroll
        for (int mi = 0; mi < 8; ++mi)
#pragma unroll
            for (int reg = 0; reg < 4; ++reg) {
                int    m = bm + wmh * 128 + mi * 16 + quad * 4 + reg;
                int    b = m >> 11, s = m & 2047;
                size_t base = ((size_t)(b * NH + h) * SEQ + s) * HD;
#pragma unroll
                for (int j = 0; j < 2; ++j) {
                    int   d1 = j * 16 + col;
                    float cs = cosT[(s << 5) + d1];
                    float sn = sinT[(s << 5) + d1];
                    float x1 = acc[mi][j][reg];
                    float x2 = acc[mi][j + 2][reg];
                    dst[base + d1]      = f2bf(x1 * cs - x2 * sn);
                    dst[base + d1 + 32] = f2bf(x1 * sn + x2 * cs);
                }
            }
    }
}

// ---------------------------------------------------------------------------
// K1 (128² fallback): QKV GEMM + RoPE. grid=(24, 64).
// ---------------------------------------------------------------------------
template <bool PRE>
__global__ __launch_bounds__(256, 2) void qkv_rope_kernel(
    const void* __restrict__ X, const void* __restrict__ W,
    const float* __restrict__ cosT, const float* __restrict__ sinT,
    short* __restrict__ Qo, short* __restrict__ Ko, short* __restrict__ VT) {
    __shared__ __align__(16) short As[2 * 8192];
    __shared__ __align__(16) short Bs[2 * 8192];
    const int bm = blockIdx.y * 128, bn = blockIdx.x * 128;
    const int lane = threadIdx.x & 63, wave = threadIdx.x >> 6;
    const int quad = lane >> 4, col = lane & 15;
    const int wm = (wave & 1) * 64, wn = (wave >> 1) * 64;

    f32x4 acc[4][4];
    if constexpr (PRE)
        gemm128_p2((const short*)X, (const short*)W, 1024, As, Bs, bm, bn, acc);
    else
        gemm128_core<true, true>(X, W, 1024, As, Bs, bm, bn, acc);

    const int n0    = bn + wn;
    const int which = n0 >> 10;
    const int h     = (n0 >> 6) & 15;

    if (which == 2) {
#pragma unroll
        for (int i = 0; i < 4; ++i) {
            int    m = bm + wm + i * 16 + quad * 4;
            int    b = m >> 11, s = m & 2047;
            size_t rowb = (size_t)(b * NH + h) * HD;
#pragma unroll
            for (int j = 0; j < 4; ++j) {
                int   d = j * 16 + col;
                s16x4 pk;
                pk[0] = f2bf(acc[i][j][0]); pk[1] = f2bf(acc[i][j][1]);
                pk[2] = f2bf(acc[i][j][2]); pk[3] = f2bf(acc[i][j][3]);
                *(s16x4*)&VT[(rowb + d) * SEQ + s] = pk;
            }
        }
    } else {
        short* dst = which ? Ko : Qo;
#pragma unroll
        for (int i = 0; i < 4; ++i)
#pragma unroll
            for (int reg = 0; reg < 4; ++reg) {
                int    m = bm + wm + i * 16 + quad * 4 + reg;
                int    b = m >> 11, s = m & 2047;
                size_t base = ((size_t)(b * NH + h) * SEQ + s) * HD;
#pragma unroll
                for (int j = 0; j < 2; ++j) {
                    int   d1 = j * 16 + col;
                    float sn, cs;
                    if constexpr (PRE) {
                        cs = cosT[(s << 5) + d1];
                        sn = sinT[(s << 5) + d1];
                    } else {
                        float inv = __expf(-0.28782313662425574f * (float)d1);
                        sincosf((float)s * inv, &sn, &cs);
                    }
                    float x1 = acc[i][j][reg];
                    float x2 = acc[i][j + 2][reg];
                    dst[base + d1]      = f2bf(x1 * cs - x2 * sn);
                    dst[base + d1 + 32] = f2bf(x1 * sn + x2 * cs);
                }
            }
    }
}

// ---------------------------------------------------------------------------
// K2: causal flash attention (round-19, unchanged). 256 thr / 4 waves;
// wave owns 32 q-rows (two strips); QBLK=128; pairing {bx,15-bx};
// XOR-swizzled Kt/Vt; defer-max THR=8 + per-lane partial l_i; setprio.
// ---------------------------------------------------------------------------
__global__ __launch_bounds__(256, 2) void attn_kernel(
    const short* __restrict__ Q, const short* __restrict__ K,
    const short* __restrict__ VT, short* __restrict__ att) {
    const int b = blockIdx.z, h = blockIdx.y;
    const int tid = threadIdx.x, wave = tid >> 6, lane = tid & 63;
    const int quad = lane >> 4, col = lane & 15;
    const size_t hoff = (size_t)(b * NH + h) * SEQ * HD;
    const short* Qp  = Q + hoff;
    const short* Kp  = K + hoff;
    const short* VTp = VT + hoff;

    __shared__ __align__(16) short Kt[64 * 64];
    __shared__ __align__(16) short Vt[64 * 64];
    __shared__ __align__(16) short Ps[4 * 32 * PS_LD];

    const int r0 = tid >> 3;
    const int r1 = r0 + 32;
    const int c8 = (tid & 7) * 8;
    const int cs = c8 ^ ((r0 & 7) << 3);
    const int swc = (col & 7) << 3;
    const int cA  = (quad * 8) ^ swc;
    const int cB  = (32 + quad * 8) ^ swc;
    short* Pw = &Ps[wave * 32 * PS_LD];

#pragma unroll 1
    for (int pass = 0; pass < 2; ++pass) {
        const int qt   = pass ? 15 - (int)blockIdx.x : (int)blockIdx.x;
        const int q0   = qt * 128 + wave * 32;
        const int tmax = 2 * qt + 1;

        bf16x8 aq[2][2];
#pragma unroll
        for (int s2 = 0; s2 < 2; ++s2) {
            aq[s2][0] = *(const bf16x8*)&Qp[(q0 + s2 * 16 + col) * HD + quad * 8];
            aq[s2][1] = *(const bf16x8*)&Qp[(q0 + s2 * 16 + col) * HD + 32 + quad * 8];
        }

        float m_i[2][4], l_i[2][4];
        f32x4 o[2][4];
#pragma unroll
        for (int s2 = 0; s2 < 2; ++s2)
#pragma unroll
            for (int rr = 0; rr < 4; ++rr) {
                m_i[s2][rr] = NEGINF; l_i[s2][rr] = 0.f;
                o[s2][rr] = f32x4{0.f, 0.f, 0.f, 0.f};
            }

        short8 ka = *(const short8*)&Kp[r0 * HD + c8];
        short8 kb = *(const short8*)&Kp[r1 * HD + c8];
        short8 va = *(const short8*)&VTp[(size_t)r0 * SEQ + c8];
        short8 vb = *(const short8*)&VTp[(size_t)r1 * SEQ + c8];

#pragma unroll 1
        for (int t = 0; t <= tmax; ++t) {
            const int kt = t * 64;
            __syncthreads();
            *(short8*)&Kt[r0 * 64 + cs] = ka;
            *(short8*)&Kt[r1 * 64 + cs] = kb;
            *(short8*)&Vt[r0 * 64 + cs] = va;
            *(short8*)&Vt[r1 * 64 + cs] = vb;
            __syncthreads();

            if (t < tmax) {
                const int kn = kt + 64;
                ka = *(const short8*)&Kp[(kn + r0) * HD + c8];
                kb = *(const short8*)&Kp[(kn + r1) * HD + c8];
                va = *(const short8*)&VTp[(size_t)r0 * SEQ + kn + c8];
                vb = *(const short8*)&VTp[(size_t)r1 * SEQ + kn + c8];
            }

            if (kt > q0 + 31) continue;

            float p[2][4][4];
            __builtin_amdgcn_s_setprio(1);
#pragma unroll
            for (int jn = 0; jn < 4; ++jn) {
                bf16x8 b0 = *(const bf16x8*)&Kt[(jn * 16 + col) * 64 + cA];
                bf16x8 b1 = *(const bf16x8*)&Kt[(jn * 16 + col) * 64 + cB];
#pragma unroll
                for (int s2 = 0; s2 < 2; ++s2) {
                    f32x4 s = f32x4{0.f, 0.f, 0.f, 0.f};
                    s = MFMA16(aq[s2][0], b0, s);
                    s = MFMA16(aq[s2][1], b1, s);
                    if (t >= 2 * qt) {
#pragma unroll
                        for (int reg = 0; reg < 4; ++reg) {
                            int qr = q0 + s2 * 16 + quad * 4 + reg;
                            int kc = kt + jn * 16 + col;
                            p[s2][jn][reg] = (kc <= qr) ? s[reg] * 0.125f : NEGINF;
                        }
                    } else {
#pragma unroll
                        for (int reg = 0; reg < 4; ++reg)
                            p[s2][jn][reg] = s[reg] * 0.125f;
                    }
                }
            }
            __builtin_amdgcn_s_setprio(0);

#pragma unroll
            for (int s2 = 0; s2 < 2; ++s2) {
                float lm[4];
#pragma unroll
                for (int reg = 0; reg < 4; ++reg)
                    lm[reg] = fmaxf(fmaxf(p[s2][0][reg], p[s2][1][reg]),
                                    fmaxf(p[s2][2][reg], p[s2][3][reg]));
                int ok = (lm[0] <= m_i[s2][0] + 8.f) & (lm[1] <= m_i[s2][1] + 8.f) &
                         (lm[2] <= m_i[s2][2] + 8.f) & (lm[3] <= m_i[s2][3] + 8.f);
                if (__all(ok)) {
#pragma unroll
                    for (int reg = 0; reg < 4; ++reg) {
                        float rs = 0.f;
#pragma unroll
                        for (int jn = 0; jn < 4; ++jn) {
                            p[s2][jn][reg] = __expf(p[s2][jn][reg] - m_i[s2][reg]);
                            rs += p[s2][jn][reg];
                        }
                        l_i[s2][reg] += rs;
                    }
                } else {
                    float alpha[4];
#pragma unroll
                    for (int reg = 0; reg < 4; ++reg) {
                        float mx = lm[reg];
#pragma unroll
                        for (int off = 8; off >= 1; off >>= 1)
                            mx = fmaxf(mx, __shfl_xor(mx, off, 64));
                        float mn   = fmaxf(m_i[s2][reg], mx);
                        alpha[reg] = __expf(m_i[s2][reg] - mn);
                        float rs = 0.f;
#pragma unroll
                        for (int jn = 0; jn < 4; ++jn) {
                            p[s2][jn][reg] = __expf(p[s2][jn][reg] - mn);
                            rs += p[s2][jn][reg];
                        }
                        l_i[s2][reg] = l_i[s2][reg] * alpha[reg] + rs;
                        m_i[s2][reg] = mn;
                    }
#pragma unroll
                    for (int jd = 0; jd < 4; ++jd)
#pragma unroll
                        for (int reg = 0; reg < 4; ++reg)
                            o[s2][jd][reg] *= alpha[reg];
                }

#pragma unroll
                for (int jn = 0; jn < 4; ++jn)
#pragma unroll
                    for (int reg = 0; reg < 4; ++reg)
                        Pw[(s2 * 16 + quad * 4 + reg) * PS_LD + jn * 16 + col] =
                            f2bf(p[s2][jn][reg]);
            }

            bf16x8 ap[2][2];
#pragma unroll
            for (int s2 = 0; s2 < 2; ++s2) {
                ap[s2][0] = *(const bf16x8*)&Pw[(s2 * 16 + col) * PS_LD + quad * 8];
                ap[s2][1] = *(const bf16x8*)&Pw[(s2 * 16 + col) * PS_LD + 32 + quad * 8];
            }
            __builtin_amdgcn_s_setprio(1);
#pragma unroll
            for (int jd = 0; jd < 4; ++jd) {
                bf16x8 bv0 = *(const bf16x8*)&Vt[(jd * 16 + col) * 64 + cA];
                bf16x8 bv1 = *(const bf16x8*)&Vt[(jd * 16 + col) * 64 + cB];
#pragma unroll
                for (int s2 = 0; s2 < 2; ++s2) {
                    o[s2][jd] = MFMA16(ap[s2][0], bv0, o[s2][jd]);
                    o[s2][jd] = MFMA16(ap[s2][1], bv1, o[s2][jd]);
                }
            }
            __builtin_amdgcn_s_setprio(0);
        }

#pragma unroll
        for (int s2 = 0; s2 < 2; ++s2) {
#pragma unroll
            for (int off = 8; off >= 1; off >>= 1)
#pragma unroll
                for (int reg = 0; reg < 4; ++reg)
                    l_i[s2][reg] += __shfl_xor(l_i[s2][reg], off, 64);
            float inv_l[4];
#pragma unroll
            for (int reg = 0; reg < 4; ++reg) inv_l[reg] = 1.f / l_i[s2][reg];
#pragma unroll
            for (int jd = 0; jd < 4; ++jd)
#pragma unroll
                for (int reg = 0; reg < 4; ++reg) {
                    int s = q0 + s2 * 16 + quad * 4 + reg;
                    att[((size_t)(b * SEQ + s)) * DIM + h * HD + jd * 16 + col] =
                        f2bf(o[s2][jd][reg] * inv_l[reg]);
                }
        }
    }
}

// ---------------------------------------------------------------------------
// K3: out = att @ Wout^T, FP32 output. grid=(8, 64). PRE: bf16 Wout + p2.
// ---------------------------------------------------------------------------
template <bool PRE>
__global__ __launch_bounds__(256, 2) void out_gemm_kernel(
    const short* __restrict__ A, const void* __restrict__ W,
    float* __restrict__ out) {
    __shared__ __align__(16) short As[2 * 8192];
    __shared__ __align__(16) short Bs[2 * 8192];
    const int bm = blockIdx.y * 128, bn = blockIdx.x * 128;
    const int lane = threadIdx.x & 63, wave = threadIdx.x >> 6;
    const int quad = lane >> 4, col = lane & 15;
    const int wm = (wave & 1) * 64, wn = (wave >> 1) * 64;

    f32x4 acc[4][4];
    if constexpr (PRE)
        gemm128_p2(A, (const short*)W, 1024, As, Bs, bm, bn, acc);
    else
        gemm128_core<false, true>(A, W, 1024, As, Bs, bm, bn, acc);

#pragma unroll
    for (int i = 0; i < 4; ++i)
#pragma unroll
        for (int reg = 0; reg < 4; ++reg) {
            int    m    = bm + wm + i * 16 + quad * 4 + reg;
            size_t base = (size_t)m * DIM + bn + wn;
#pragma unroll
            for (int j = 0; j < 4; ++j)
                out[base + j * 16 + col] = acc[i][j][reg];
        }
}

// ---------------------------------------------------------------------------
extern "C" void kernel_launch(void* const* d_in, const int* in_sizes, int n_in,
                              void* d_out, int out_size, void* d_ws, size_t ws_size,
                              hipStream_t stream) {
    const float* x    = nullptr;
    const float* Wqkv = nullptr;
    const float* Wout = nullptr;
    for (int i = 0; i < n_in; ++i) {
        switch (in_sizes[i]) {
            case 8388608: x    = (const float*)d_in[i]; break;
            case 3145728: Wqkv = (const float*)d_in[i]; break;
            case 1048576: Wout = (const float*)d_in[i]; break;
            default: break;
        }
    }
    if (!x || !Wqkv || !Wout) return;

    short* Q  = (short*)d_ws;
    short* K  = Q + BHSD;
    short* VT = K + BHSD;
    float* out = (float*)d_out;

    const size_t need_pre = (size_t)4 * BHSD * sizeof(short)
                          + BHSD * sizeof(short)
                          + (size_t)3145728 * sizeof(short)
                          + (size_t)1048576 * sizeof(short)
                          + (size_t)2 * 65536 * sizeof(float);

    // opt-in to 128 KiB dynamic LDS for the 256² K1 (once); graceful fallback
    static int big_lds = -1;
    if (big_lds < 0) {
        big_lds = (hipFuncSetAttribute((const void*)qkv_rope_256,
                       hipFuncAttributeMaxDynamicSharedMemorySize,
                       131072) == hipSuccess) ? 1 : 0;
    }

    if (ws_size >= need_pre) {
        short* att  = VT + BHSD;
        short* Xb   = att + BHSD;
        short* Wqb  = Xb + BHSD;
        short* Wob  = Wqb + 3145728;
        float* cosT = (float*)(Wob + 1048576);
        float* sinT = cosT + 65536;

        prep_kernel<<<dim3(2048), 256, 0, stream>>>(x, Wqkv, Wout, Xb, Wqb, Wob, cosT, sinT);
        if (big_lds)
            qkv_rope_256<<<dim3(12, 32), 512, 131072, stream>>>(
                Xb, Wqb, cosT, sinT, Q, K, VT);
        else
            qkv_rope_kernel<true><<<dim3(24, 64), 256, 0, stream>>>(
                Xb, Wqb, cosT, sinT, Q, K, VT);
        attn_kernel<<<dim3(8, NH, BATCH), 256, 0, stream>>>(Q, K, VT, att);
        out_gemm_kernel<true><<<dim3(8, 64), 256, 0, stream>>>(att, Wob, out);
    } else {
        qkv_rope_kernel<false><<<dim3(24, 64), 256, 0, stream>>>(
            x, Wqkv, nullptr, nullptr, Q, K, VT);

        const bool direct = ws_size >= (size_t)4 * BHSD * sizeof(short);
        short* att_dst = direct ? (VT + BHSD) : (short*)d_out;
        attn_kernel<<<dim3(8, NH, BATCH), 256, 0, stream>>>(Q, K, VT, att_dst);

        short* att = att_dst;
        if (!direct) {
            att = (short*)d_ws;
            hipMemcpyAsync(att, att_dst, BHSD * sizeof(short), hipMemcpyDeviceToDevice, stream);
        }
        out_gemm_kernel<false><<<dim3(8, 64), 256, 0, stream>>>(att, Wout, out);
    }
}